// Round 1
// baseline (141.869 us; speedup 1.0000x reference)
//
#include <hip/hip_runtime.h>

#define NQ 13
#define DIM (1 << NQ)      // 8192 amplitudes
#define NL 2
#define NBATCH 512
#define TPB 256

// One block per batch element. State (re/im) lives in LDS: 2 * 8192 * 4B = 64 KiB
// -> exactly 2 blocks/CU on MI355X (160 KiB LDS), and 512 blocks = 2 per CU.
__global__ __launch_bounds__(TPB) void qsim_kernel(const float* __restrict__ x,
                                                   const float* __restrict__ w,
                                                   float* __restrict__ out) {
    __shared__ float sre[DIM];
    __shared__ float sim[DIM];
    __shared__ float red[4][NQ];

    const int b = blockIdx.x;
    const int t = threadIdx.x;

    // init |00..0>
    for (int i = t; i < DIM; i += TPB) { sre[i] = 0.0f; sim[i] = 0.0f; }
    if (t == 0) sre[0] = 1.0f;
    __syncthreads();

    for (int l = 0; l < NL; ++l) {
        // --- single-qubit fused gates: U = RZ(w2) * RY(x*w1) * RX(x*w0) ---
        for (int q = 0; q < NQ; ++q) {
            const float xv = x[b * NQ + q];
            const float w0 = w[(l * NQ + q) * 3 + 0];
            const float w1 = w[(l * NQ + q) * 3 + 1];
            const float w2 = w[(l * NQ + q) * 3 + 2];
            const float tx = 0.5f * xv * w0;
            const float ty = 0.5f * xv * w1;
            const float tz = 0.5f * w2;
            const float cx = cosf(tx), sx = sinf(tx);
            const float cy = cosf(ty), sy = sinf(ty);
            const float cz = cosf(tz), sz = sinf(tz);
            // M = RY * RX:
            //  M00 = cy*cx + i sy*sx   M01 = -sy*cx - i cy*sx
            //  M10 = sy*cx - i cy*sx   M11 =  cy*cx - i sy*sx
            const float m00r = cy * cx, m00i = sy * sx;
            const float m01r = -sy * cx, m01i = -cy * sx;
            const float m10r = sy * cx, m10i = -cy * sx;
            const float m11r = cy * cx, m11i = -sy * sx;
            // RZ: row0 *= e^{-i tz} = (cz - i sz); row1 *= e^{+i tz} = (cz + i sz)
            const float u00r = m00r * cz + m00i * sz, u00i = m00i * cz - m00r * sz;
            const float u01r = m01r * cz + m01i * sz, u01i = m01i * cz - m01r * sz;
            const float u10r = m10r * cz - m10i * sz, u10i = m10i * cz + m10r * sz;
            const float u11r = m11r * cz - m11i * sz, u11i = m11i * cz + m11r * sz;

            const int sh = NQ - 1 - q;        // log2(stride); wire 0 = MSB
            const int s = 1 << sh;
            #pragma unroll 4
            for (int p = t; p < DIM / 2; p += TPB) {
                const int i0 = ((p >> sh) << (sh + 1)) | (p & (s - 1));
                const int i1 = i0 | s;
                const float ar = sre[i0], ai = sim[i0];
                const float br = sre[i1], bi = sim[i1];
                sre[i0] = u00r * ar - u00i * ai + u01r * br - u01i * bi;
                sim[i0] = u00r * ai + u00i * ar + u01r * bi + u01i * br;
                sre[i1] = u10r * ar - u10i * ai + u11r * br - u11i * bi;
                sim[i1] = u10r * ai + u10i * ar + u11r * bi + u11i * br;
            }
            __syncthreads();
        }
        // --- CNOT chain c -> c+1 (pure swap where control bit == 1) ---
        for (int c = 0; c < NQ - 1; ++c) {
            const int pt = NQ - 2 - c;        // target bit position (wire c+1)
            const int s = 1 << pt;            // target stride; control bit = 2*s
            #pragma unroll 4
            for (int p = t; p < DIM / 4; p += TPB) {
                const int low = p & (s - 1);
                const int rest = p >> pt;
                const int i0 = (rest << (pt + 2)) | (s << 1) | low; // control=1, target=0
                const int i1 = i0 | s;                              // control=1, target=1
                const float ar = sre[i0], ai = sim[i0];
                sre[i0] = sre[i1]; sim[i0] = sim[i1];
                sre[i1] = ar;      sim[i1] = ai;
            }
            __syncthreads();
        }
    }

    // --- PauliZ expvals for all 13 wires ---
    float ev[NQ];
    #pragma unroll
    for (int q = 0; q < NQ; ++q) ev[q] = 0.0f;
    for (int i = t; i < DIM; i += TPB) {
        const float pr = sre[i] * sre[i] + sim[i] * sim[i];
        #pragma unroll
        for (int q = 0; q < NQ; ++q)
            ev[q] += ((i >> (NQ - 1 - q)) & 1) ? -pr : pr;
    }
    // wave64 shuffle reduce
    #pragma unroll
    for (int q = 0; q < NQ; ++q) {
        float v = ev[q];
        for (int off = 32; off > 0; off >>= 1) v += __shfl_down(v, off, 64);
        ev[q] = v;
    }
    const int wave = t >> 6, lane = t & 63;
    if (lane == 0) {
        #pragma unroll
        for (int q = 0; q < NQ; ++q) red[wave][q] = ev[q];
    }
    __syncthreads();
    if (t < NQ) {
        out[b * NQ + t] = red[0][t] + red[1][t] + red[2][t] + red[3][t];
    }
}

extern "C" void kernel_launch(void* const* d_in, const int* in_sizes, int n_in,
                              void* d_out, int out_size, void* d_ws, size_t ws_size,
                              hipStream_t stream) {
    const float* x = (const float*)d_in[0];   // (512, 13) float32
    const float* w = (const float*)d_in[1];   // (2, 13, 3) float32
    float* out = (float*)d_out;               // (512, 13) float32
    qsim_kernel<<<NBATCH, TPB, 0, stream>>>(x, w, out);
}

// Round 3
// 109.605 us; speedup vs baseline: 1.2944x; 1.2944x over previous
//
#include <hip/hip_runtime.h>

#define NQ 13
#define DIM (1 << NQ)
#define NL 2
#define NBATCH 512
#define TPB 256
#define NLOC 32            // amplitudes per thread (local bits 0..4)

// Fused single-qubit gate U = RZ(w2) * RY(x*w1) * RX(x*w0)
struct U2 { float r00, i00, r01, i01, r10, i10, r11, i11; };

__device__ __forceinline__ U2 gate_u(const float* __restrict__ x,
                                     const float* __restrict__ w,
                                     int b, int l, int q) {
    const float xv = x[b * NQ + q];
    const float w0 = w[(l * NQ + q) * 3 + 0];
    const float w1 = w[(l * NQ + q) * 3 + 1];
    const float w2 = w[(l * NQ + q) * 3 + 2];
    const float tx = 0.5f * xv * w0;
    const float ty = 0.5f * xv * w1;
    const float tz = 0.5f * w2;
    const float cx = __cosf(tx), sx = __sinf(tx);
    const float cy = __cosf(ty), sy = __sinf(ty);
    const float cz = __cosf(tz), sz = __sinf(tz);
    // M = RY*RX
    const float m00r = cy * cx,  m00i = sy * sx;
    const float m01r = -sy * cx, m01i = -cy * sx;
    const float m10r = sy * cx,  m10i = -cy * sx;
    const float m11r = cy * cx,  m11i = -sy * sx;
    // U = RZ * M : row0 *= (cz - i sz), row1 *= (cz + i sz)
    U2 u;
    u.r00 = m00r * cz + m00i * sz;  u.i00 = m00i * cz - m00r * sz;
    u.r01 = m01r * cz + m01i * sz;  u.i01 = m01i * cz - m01r * sz;
    u.r10 = m10r * cz - m10i * sz;  u.i10 = m10i * cz + m10r * sz;
    u.r11 = m11r * cz - m11i * sz;  u.i11 = m11i * cz + m11r * sz;
    return u;
}

// i (13 bits) = t[7:0] : k[4:0].  i bit sh=12-q is: local (sh 0..4, q 12..8),
// lane bit sh-5 (sh 5..10, q 7..2), wave/thread bit (sh 11..12, q 1..0).
__global__ __launch_bounds__(TPB) void qsim_kernel(const float* __restrict__ x,
                                                   const float* __restrict__ w,
                                                   float* __restrict__ out) {
    __shared__ float2 xbuf[NLOC * TPB];   // 64 KiB exchange buffer, [k][t] layout
    __shared__ float rbuf[4][NQ];

    const int b = blockIdx.x;
    const int t = threadIdx.x;
    const int lane = t & 63;

    float re[NLOC], im[NLOC];

    // ================= Layer 0: single-qubit gates applied to |0..0> ====
    // amplitude(i) = prod_q U_q[bit(i, 12-q)][0]  -> build product state in regs.
    float cr = 1.0f, ci = 0.0f;
    #pragma unroll
    for (int q = 0; q < 8; ++q) {          // thread-bit qubits: i bit 12-q = t bit 7-q
        U2 u = gate_u(x, w, b, 0, q);
        const int bit = (t >> (7 - q)) & 1;
        const float fr = bit ? u.r10 : u.r00;
        const float fi = bit ? u.i10 : u.i00;
        const float nr = cr * fr - ci * fi;
        const float ni = cr * fi + ci * fr;
        cr = nr; ci = ni;
    }
    re[0] = cr; im[0] = ci;
    #pragma unroll
    for (int j = 0; j < 5; ++j) {          // local bit j <-> qubit 12-j
        U2 u = gate_u(x, w, b, 0, 12 - j);
        const int m = 1 << j;
        #pragma unroll
        for (int k = 0; k < 16; ++k) {
            if (k < m) {
                const float ar = re[k], ai = im[k];
                re[k + m] = ar * u.r10 - ai * u.i10;
                im[k + m] = ar * u.i10 + ai * u.r10;
                re[k]     = ar * u.r00 - ai * u.i00;
                im[k]     = ar * u.i00 + ai * u.r00;
            }
        }
    }

    // ====================== per-layer CNOT chain + layer-1 gates ========
    for (int l = 0; l < NL; ++l) {
        if (l == 1) {
            // ---- layer 1 single-qubit gates ----
            // q=0,1: thread bits 7,6 -> LDS exchange
            #pragma unroll
            for (int q = 0; q < 2; ++q) {
                U2 u = gate_u(x, w, b, 1, q);
                const int mask = (q == 0) ? 128 : 64;
                const int bit = (t & mask) ? 1 : 0;
                const float aor = bit ? u.r11 : u.r00;
                const float aoi = bit ? u.i11 : u.i00;
                const float bpr = bit ? u.r10 : u.r01;
                const float bpi = bit ? u.i10 : u.i01;
                __syncthreads();
                #pragma unroll
                for (int k = 0; k < NLOC; ++k)
                    xbuf[k * TPB + t] = make_float2(re[k], im[k]);
                __syncthreads();
                const int p = t ^ mask;
                #pragma unroll
                for (int k = 0; k < NLOC; ++k) {
                    const float2 pv = xbuf[k * TPB + p];
                    const float nr = aor * re[k] - aoi * im[k] + bpr * pv.x - bpi * pv.y;
                    const float ni = aor * im[k] + aoi * re[k] + bpr * pv.y + bpi * pv.x;
                    re[k] = nr; im[k] = ni;
                }
            }
            // q=2..7: lane bits -> shuffle
            for (int q = 2; q <= 7; ++q) {
                U2 u = gate_u(x, w, b, 1, q);
                const int m = 1 << (7 - q);
                const int bit = (lane >> (7 - q)) & 1;
                const float aor = bit ? u.r11 : u.r00;
                const float aoi = bit ? u.i11 : u.i00;
                const float bpr = bit ? u.r10 : u.r01;
                const float bpi = bit ? u.i10 : u.i01;
                #pragma unroll
                for (int k = 0; k < NLOC; ++k) {
                    const float prr = __shfl_xor(re[k], m, 64);
                    const float pii = __shfl_xor(im[k], m, 64);
                    const float nr = aor * re[k] - aoi * im[k] + bpr * prr - bpi * pii;
                    const float ni = aor * im[k] + aoi * re[k] + bpr * pii + bpi * prr;
                    re[k] = nr; im[k] = ni;
                }
            }
            // q=8..12: local bits -> register 2x2
            #pragma unroll
            for (int j = 4; j >= 0; --j) {
                U2 u = gate_u(x, w, b, 1, 12 - j);
                const int m = 1 << j;
                #pragma unroll
                for (int k = 0; k < NLOC; ++k) {
                    if (((k >> j) & 1) == 0) {
                        const int k1 = k | m;
                        const float ar = re[k], ai = im[k];
                        const float br = re[k1], bi = im[k1];
                        re[k]  = u.r00 * ar - u.i00 * ai + u.r01 * br - u.i01 * bi;
                        im[k]  = u.r00 * ai + u.i00 * ar + u.r01 * bi + u.i01 * br;
                        re[k1] = u.r10 * ar - u.i10 * ai + u.r11 * br - u.i11 * bi;
                        im[k1] = u.r10 * ai + u.i10 * ar + u.r11 * bi + u.i11 * br;
                    }
                }
            }
        }

        // ---- CNOT chain c -> c+1, c = 0..11 (order matters) ----
        // c=0: control i-bit 12 (t bit 7), target i-bit 11 (t bit 6): LDS swap
        __syncthreads();
        if (t & 128) {
            #pragma unroll
            for (int k = 0; k < NLOC; ++k)
                xbuf[k * TPB + (t & 127)] = make_float2(re[k], im[k]);
        }
        __syncthreads();
        if (t & 128) {
            #pragma unroll
            for (int k = 0; k < NLOC; ++k) {
                const float2 pv = xbuf[k * TPB + ((t & 127) ^ 64)];
                re[k] = pv.x; im[k] = pv.y;
            }
        }
        // c=1: control t bit 6 (wave-uniform), target lane bit 5: shuffle swap
        if (t & 64) {
            #pragma unroll
            for (int k = 0; k < NLOC; ++k) {
                re[k] = __shfl_xor(re[k], 32, 64);
                im[k] = __shfl_xor(im[k], 32, 64);
            }
        }
        // c=2..6: control lane bit pt-4, target lane bit pt-5: predicated shuffle
        for (int c = 2; c <= 6; ++c) {
            const int pt = 11 - c;                 // target i-bit (lane bit pt-5)
            const int tm = 1 << (pt - 5);
            const int ctrl = (lane >> (pt - 4)) & 1;
            #pragma unroll
            for (int k = 0; k < NLOC; ++k) {
                const float prr = __shfl_xor(re[k], tm, 64);
                const float pii = __shfl_xor(im[k], tm, 64);
                re[k] = ctrl ? prr : re[k];
                im[k] = ctrl ? pii : im[k];
            }
        }
        // c=7: control t bit 0, target local bit 4: predicated register swap
        {
            const bool ctrl = (t & 1);
            #pragma unroll
            for (int k = 0; k < 16; ++k) {
                const float tr = re[k], ti = im[k];
                const float ur = re[k + 16], ui = im[k + 16];
                re[k]      = ctrl ? ur : tr;
                im[k]      = ctrl ? ui : ti;
                re[k + 16] = ctrl ? tr : ur;
                im[k + 16] = ctrl ? ti : ui;
            }
        }
        // c=8..11: both bits local -> compile-time register permutation (free)
        #pragma unroll
        for (int c = 8; c <= 11; ++c) {
            const int pc = 12 - c, pt = pc - 1;
            #pragma unroll
            for (int k = 0; k < NLOC; ++k) {
                if (((k >> pc) & 1) && !((k >> pt) & 1)) {
                    const int k2 = k | (1 << pt);
                    const float tr = re[k], ti = im[k];
                    re[k] = re[k2]; im[k] = im[k2];
                    re[k2] = tr;    im[k2] = ti;
                }
            }
        }
    }

    // ======================= PauliZ expvals =============================
    float tot = 0.0f;
    float ls[5] = {0.f, 0.f, 0.f, 0.f, 0.f};   // signed sums, local bit j -> qubit 12-j
    #pragma unroll
    for (int k = 0; k < NLOC; ++k) {
        const float pr = re[k] * re[k] + im[k] * im[k];
        tot += pr;
        #pragma unroll
        for (int j = 0; j < 5; ++j)
            ls[j] += ((k >> j) & 1) ? -pr : pr;
    }
    float ev[NQ];
    #pragma unroll
    for (int q = 0; q < 8; ++q)                 // i bit 12-q = t bit 7-q
        ev[q] = ((t >> (7 - q)) & 1) ? -tot : tot;
    #pragma unroll
    for (int q = 8; q < NQ; ++q)
        ev[q] = ls[12 - q];

    #pragma unroll
    for (int q = 0; q < NQ; ++q) {
        float v = ev[q];
        #pragma unroll
        for (int off = 32; off; off >>= 1) v += __shfl_xor(v, off, 64);
        ev[q] = v;
    }
    if (lane == 0) {
        #pragma unroll
        for (int q = 0; q < NQ; ++q) rbuf[t >> 6][q] = ev[q];
    }
    __syncthreads();
    if (t < NQ) out[b * NQ + t] = rbuf[0][t] + rbuf[1][t] + rbuf[2][t] + rbuf[3][t];
}

extern "C" void kernel_launch(void* const* d_in, const int* in_sizes, int n_in,
                              void* d_out, int out_size, void* d_ws, size_t ws_size,
                              hipStream_t stream) {
    const float* x = (const float*)d_in[0];   // (512, 13) float32
    const float* w = (const float*)d_in[1];   // (2, 13, 3) float32
    float* out = (float*)d_out;               // (512, 13) float32
    qsim_kernel<<<NBATCH, TPB, 0, stream>>>(x, w, out);
}

// Round 4
// 88.157 us; speedup vs baseline: 1.6093x; 1.2433x over previous
//
#include <hip/hip_runtime.h>

#define NQ 13
#define NL 2
#define NBATCH 512
#define TPB 256
#define NLOC 32            // amplitudes per thread (local bits 0..4)

// Fused single-qubit gate U = RZ(w2) * RY(x*w1) * RX(x*w0)
struct U2 { float r00, i00, r01, i01, r10, i10, r11, i11; };

// Index map: i (13 bits) = t[7:0] : k[4:0]. Qubit q <-> bit 12-q.
// CNOT chain (c -> c+1, c=0..11) == prefix-XOR permutation P (MSB-first);
// inverse is Gray code: src(j) = j ^ (j >> 1).
__global__ __launch_bounds__(TPB) void qsim_kernel(const float* __restrict__ x,
                                                   const float* __restrict__ w,
                                                   float* __restrict__ out) {
    __shared__ float2 xbuf[NLOC * TPB];   // 64 KiB state image, [k][t] layout
    __shared__ U2 ug[NL * NQ];            // 26 fused gate matrices
    __shared__ float rbuf[4][NQ];

    const int b = blockIdx.x;
    const int t = threadIdx.x;
    const int lane = t & 63;

    // ---------- Phase 0: cooperative gate-matrix computation ----------
    if (t < NL * NQ) {
        const int l = t / NQ, q = t - l * NQ;
        const float xv = x[b * NQ + q];
        const float tx = 0.5f * xv * w[(l * NQ + q) * 3 + 0];
        const float ty = 0.5f * xv * w[(l * NQ + q) * 3 + 1];
        const float tz = 0.5f * w[(l * NQ + q) * 3 + 2];
        const float cx = __cosf(tx), sx = __sinf(tx);
        const float cy = __cosf(ty), sy = __sinf(ty);
        const float cz = __cosf(tz), sz = __sinf(tz);
        // M = RY*RX
        const float m00r = cy * cx,  m00i = sy * sx;
        const float m01r = -sy * cx, m01i = -cy * sx;
        const float m10r = sy * cx,  m10i = -cy * sx;
        const float m11r = cy * cx,  m11i = -sy * sx;
        // U = RZ*M : row0 *= (cz - i sz), row1 *= (cz + i sz)
        U2 u;
        u.r00 = m00r * cz + m00i * sz;  u.i00 = m00i * cz - m00r * sz;
        u.r01 = m01r * cz + m01i * sz;  u.i01 = m01i * cz - m01r * sz;
        u.r10 = m10r * cz - m10i * sz;  u.i10 = m10i * cz + m10r * sz;
        u.r11 = m11r * cz - m11i * sz;  u.i11 = m11i * cz + m11r * sz;
        ug[t] = u;
    }
    __syncthreads();

    // ---------- Phase 1: layer-0 gates on |0..0> -> product state ----------
    float re[NLOC], im[NLOC];
    {
        float cr = 1.0f, ci = 0.0f;
        #pragma unroll
        for (int q = 0; q < 8; ++q) {          // thread-bit qubits
            const U2 u = ug[q];
            const int bit = (t >> (7 - q)) & 1;
            const float fr = bit ? u.r10 : u.r00;
            const float fi = bit ? u.i10 : u.i00;
            const float nr = cr * fr - ci * fi;
            const float ni = cr * fi + ci * fr;
            cr = nr; ci = ni;
        }
        re[0] = cr; im[0] = ci;
        #pragma unroll
        for (int j = 0; j < 5; ++j) {          // local bit j <-> qubit 12-j
            const U2 u = ug[12 - j];
            const int m = 1 << j;
            #pragma unroll
            for (int k = 0; k < 16; ++k) {
                if (k < m) {
                    const float ar = re[k], ai = im[k];
                    re[k + m] = ar * u.r10 - ai * u.i10;
                    im[k + m] = ar * u.i10 + ai * u.r10;
                    re[k]     = ar * u.r00 - ai * u.i00;
                    im[k]     = ar * u.i00 + ai * u.r00;
                }
            }
        }
    }

    // ---------- Phase 2: fused [L0 CNOT chain (Gray gather)] + [L1 gates q0,q1] ----------
    #pragma unroll
    for (int k = 0; k < NLOC; ++k)
        xbuf[k * TPB + t] = make_float2(re[k], im[k]);
    __syncthreads();
    {
        const U2 u0 = ug[NQ + 0], u1 = ug[NQ + 1];
        const int abit = (t >> 7) & 1, bbit = (t >> 6) & 1;
        // U0 row `abit`, U1 row `bbit`
        const float A0r = abit ? u0.r10 : u0.r00, A0i = abit ? u0.i10 : u0.i00;
        const float A1r = abit ? u0.r11 : u0.r01, A1i = abit ? u0.i11 : u0.i01;
        const float B0r = bbit ? u1.r10 : u1.r00, B0i = bbit ? u1.i10 : u1.i00;
        const float B1r = bbit ? u1.r11 : u1.r01, B1i = bbit ? u1.i11 : u1.i01;
        float c_r[4], c_i[4];
        c_r[0] = A0r * B0r - A0i * B0i;  c_i[0] = A0r * B0i + A0i * B0r;  // (a'=0,b'=0)
        c_r[1] = A0r * B1r - A0i * B1i;  c_i[1] = A0r * B1i + A0i * B1r;  // (0,1)
        c_r[2] = A1r * B0r - A1i * B0i;  c_i[2] = A1r * B0i + A1i * B0r;  // (1,0)
        c_r[3] = A1r * B1r - A1i * B1i;  c_i[3] = A1r * B1i + A1i * B1r;  // (1,1)
        int ts[4];
        #pragma unroll
        for (int s = 0; s < 4; ++s) {
            const int tp = (t & 63) | (((s >> 1) & 1) << 7) | ((s & 1) << 6);
            ts[s] = (tp ^ (tp >> 1)) & 255;   // Gray source thread of sector (a',b')
        }
        const int kx = (t & 1) << 4;           // bit4 of src k = k4 ^ t0
        #pragma unroll
        for (int k = 0; k < NLOC; ++k) {
            const int gk = (k ^ (k >> 1)) ^ kx;
            const float2 v0 = xbuf[gk * TPB + ts[0]];
            const float2 v1 = xbuf[gk * TPB + ts[1]];
            const float2 v2 = xbuf[gk * TPB + ts[2]];
            const float2 v3 = xbuf[gk * TPB + ts[3]];
            re[k] = c_r[0] * v0.x - c_i[0] * v0.y + c_r[1] * v1.x - c_i[1] * v1.y
                  + c_r[2] * v2.x - c_i[2] * v2.y + c_r[3] * v3.x - c_i[3] * v3.y;
            im[k] = c_r[0] * v0.y + c_i[0] * v0.x + c_r[1] * v1.y + c_i[1] * v1.x
                  + c_r[2] * v2.y + c_i[2] * v2.x + c_r[3] * v3.y + c_i[3] * v3.x;
        }
    }

    // ---------- Phase 3: L1 gates q=2..7 (lane bits) via shuffle ----------
    #pragma unroll
    for (int q = 2; q <= 7; ++q) {
        const U2 u = ug[NQ + q];
        const int m = 1 << (7 - q);
        const int bit = (lane >> (7 - q)) & 1;
        const float aor = bit ? u.r11 : u.r00;
        const float aoi = bit ? u.i11 : u.i00;
        const float bpr = bit ? u.r10 : u.r01;
        const float bpi = bit ? u.i10 : u.i01;
        #pragma unroll
        for (int k = 0; k < NLOC; ++k) {
            const float prr = __shfl_xor(re[k], m, 64);
            const float pii = __shfl_xor(im[k], m, 64);
            const float nr = aor * re[k] - aoi * im[k] + bpr * prr - bpi * pii;
            im[k] = aor * im[k] + aoi * re[k] + bpr * pii + bpi * prr;
            re[k] = nr;
        }
    }

    // ---------- Phase 4: L1 gates q=8..12 (local bits) ----------
    #pragma unroll
    for (int j = 4; j >= 0; --j) {
        const U2 u = ug[NQ + 12 - j];
        const int m = 1 << j;
        #pragma unroll
        for (int k = 0; k < NLOC; ++k) {
            if (((k >> j) & 1) == 0) {
                const int k1 = k | m;
                const float ar = re[k], ai = im[k];
                const float br = re[k1], bi = im[k1];
                re[k]  = u.r00 * ar - u.i00 * ai + u.r01 * br - u.i01 * bi;
                im[k]  = u.r00 * ai + u.i00 * ar + u.r01 * bi + u.i01 * br;
                re[k1] = u.r10 * ar - u.i10 * ai + u.r11 * br - u.i11 * bi;
                im[k1] = u.r10 * ai + u.i10 * ar + u.r11 * bi + u.i11 * br;
            }
        }
    }

    // ---------- Phase 5: measurement; L1 CNOT chain folded into signs ----------
    // After-chain prob at j equals pre-chain prob at j^(j>>1), so
    // ev[q] = sum_i (-1)^{parity(top (q+1) bits of i)} * p(i).
    float tot = 0.0f;
    float ls[5] = {0.f, 0.f, 0.f, 0.f, 0.f};
    #pragma unroll
    for (int k = 0; k < NLOC; ++k) {
        const float pr = re[k] * re[k] + im[k] * im[k];
        tot += pr;
        #pragma unroll
        for (int idx = 0; idx < 5; ++idx)      // qubit q=8+idx: k bits [4 .. 4-idx]
            ls[idx] += (__popc(k >> (4 - idx)) & 1) ? -pr : pr;
    }
    const int pt = __popc(t) & 1;
    float ev[NQ];
    #pragma unroll
    for (int q = 0; q < 8; ++q)                // t bits [7 .. 7-q]
        ev[q] = (__popc(t >> (7 - q)) & 1) ? -tot : tot;
    #pragma unroll
    for (int q = 8; q < NQ; ++q)
        ev[q] = pt ? -ls[q - 8] : ls[q - 8];

    #pragma unroll
    for (int q = 0; q < NQ; ++q) {
        float v = ev[q];
        #pragma unroll
        for (int off = 32; off; off >>= 1) v += __shfl_xor(v, off, 64);
        ev[q] = v;
    }
    if (lane == 0) {
        #pragma unroll
        for (int q = 0; q < NQ; ++q) rbuf[t >> 6][q] = ev[q];
    }
    __syncthreads();
    if (t < NQ) out[b * NQ + t] = rbuf[0][t] + rbuf[1][t] + rbuf[2][t] + rbuf[3][t];
}

extern "C" void kernel_launch(void* const* d_in, const int* in_sizes, int n_in,
                              void* d_out, int out_size, void* d_ws, size_t ws_size,
                              hipStream_t stream) {
    const float* x = (const float*)d_in[0];   // (512, 13) float32
    const float* w = (const float*)d_in[1];   // (2, 13, 3) float32
    float* out = (float*)d_out;               // (512, 13) float32
    qsim_kernel<<<NBATCH, TPB, 0, stream>>>(x, w, out);
}